// Round 2
// baseline (1072.487 us; speedup 1.0000x reference)
//
#include <hip/hip_runtime.h>
#include <stdint.h>

#define N_OUT 100000
#define CIN 16
#define COUT 32
#define VPB 16           // voxels per block
#define ACC_STRIDE 1028  // 1024 + 4 dword pad
#define THREADS 512

// MFMA K-index permutation: k_mfma = ch*64 + tap  (ch: 0..15, tap: 0..63)
// acc offset for k_mfma is the identity (ch*64 + tap), so phase-2 A-reads are
// contiguous b128; the scatter writes land at bank (4v + tap) % 32 -> uniform.

typedef __attribute__((ext_vector_type(4))) float f32x4;
typedef __attribute__((ext_vector_type(8))) __bf16 bf16x8;

__device__ __forceinline__ float clampf(float x, float lo, float hi) {
  return fminf(fmaxf(x, lo), hi);
}

// prep: kernel fp32 [64 taps][16 cin][32 cout] -> bf16 MFMA B-fragments in
// permuted K order. wsB[((kchunk*2 + ntile)*64 + lane)*8 + j] where
// k_mfma = kchunk*32 + (lane>>4)*8 + j ; tap = k & 63 ; cin = k >> 6 ;
// o = ntile*16 + (lane&15)
__global__ void prep_kernel(const float* __restrict__ kern, __bf16* __restrict__ wsB) {
  int t = blockIdx.x * blockDim.x + threadIdx.x;  // 0..32767
  int j = t & 7;
  int lane = (t >> 3) & 63;
  int ntile = (t >> 9) & 1;
  int kchunk = t >> 10;
  int k = kchunk * 32 + (lane >> 4) * 8 + j;
  int tap = k & 63;
  int cin = k >> 6;
  int o = ntile * 16 + (lane & 15);
  wsB[t] = (__bf16)kern[(tap * CIN + cin) * COUT + o];
}

__global__ __launch_bounds__(THREADS, 4) void cconv_kernel(
    const float* __restrict__ feats, const float* __restrict__ inp_pts,
    const float* __restrict__ out_pts, const float* __restrict__ out_ext,
    const float* __restrict__ scale, const float* __restrict__ ndist,
    const int* __restrict__ nidx, const int* __restrict__ rsp,
    const float* __restrict__ bias, const __bf16* __restrict__ wsB,
    float* __restrict__ out) {
  __shared__ float acc[VPB * ACC_STRIDE];  // 65792 B
  __shared__ int rsp_s[VPB + 1];
  __shared__ float denS[VPB];

  int tid = threadIdx.x;
  int vbase = blockIdx.x * VPB;

  if (tid < VPB + 1) rsp_s[tid] = rsp[vbase + tid];
  if (tid < VPB) denS[tid] = 0.f;
  for (int i = tid; i < VPB * ACC_STRIDE / 4; i += THREADS)
    ((f32x4*)acc)[i] = (f32x4){0.f, 0.f, 0.f, 0.f};
  __syncthreads();

  int rs0 = rsp_s[0];
  int te = rsp_s[VPB] - rs0;  // edges in this block

  // ---- phase 1: geometry + atomic dense scatter (one task per edge-half) ----
  for (int t2 = tid; t2 < 2 * te; t2 += THREADS) {
    int el = t2, cg = 0;
    if (el >= te) { el -= te; cg = 1; }
    // find voxel: largest v with rsp_s[v] <= rs0+el
    int eg = rs0 + el;
    int v = 0;
    if (rsp_s[v + 8] <= eg) v += 8;
    if (rsp_s[v + 4] <= eg) v += 4;
    if (rsp_s[v + 2] <= eg) v += 2;
    if (rsp_s[v + 1] <= eg) v += 1;
    int n = vbase + v;

    int e = eg;
    int nbr = nidx[e];
    float dsq = ndist[e];
    float p6 = 1.f - dsq;
    p6 = p6 * p6 * p6;
    p6 = clampf(p6, 0.f, 1.f);
    float imp = scale[e] * p6;
    float inv = 2.f / out_ext[n];
    float rx = (inp_pts[nbr * 3 + 0] - out_pts[n * 3 + 0]) * inv;
    float ry = (inp_pts[nbr * 3 + 1] - out_pts[n * 3 + 1]) * inv;
    float rz = (inp_pts[nbr * 3 + 2] - out_pts[n * 3 + 2]) * inv;
    float l2 = sqrtf(rx * rx + ry * ry + rz * rz);
    float linf = fmaxf(fabsf(rx), fmaxf(fabsf(ry), fabsf(rz)));
    float s = (linf > 0.f) ? (l2 / fmaxf(linf, 1e-12f)) : 0.f;
    float qx = clampf(rx * s, -1.f, 1.f);
    float qy = clampf(ry * s, -1.f, 1.f);
    float qz = clampf(rz * s, -1.f, 1.f);
    float tx = (qx + 1.f) * 1.5f, ty = (qy + 1.f) * 1.5f, tz = (qz + 1.f) * 1.5f;
    float fx0 = clampf(floorf(tx), 0.f, 2.f);
    float fy0 = clampf(floorf(ty), 0.f, 2.f);
    float fz0 = clampf(floorf(tz), 0.f, 2.f);
    int ix = (int)fx0, iy = (int)fy0, iz = (int)fz0;
    float fx = tx - fx0, fy = ty - fy0, fz = tz - fz0;
    int cbase = ix * 16 + iy * 4 + iz;

    if (cg == 0) atomicAdd(&denS[v], imp);

    const f32x4* fp = (const f32x4*)(feats + nbr * CIN + cg * 8);
    f32x4 f0 = fp[0], f1 = fp[1];
    float fv[8] = {f0[0], f0[1], f0[2], f0[3], f1[0], f1[1], f1[2], f1[3]};
    float wx[2] = {(1.f - fx) * imp, fx * imp};
    float wy[2] = {1.f - fy, fy};
    float wz[2] = {1.f - fz, fz};
    int vb = v * ACC_STRIDE + cg * 8 * 64;
#pragma unroll
    for (int ca = 0; ca < 2; ++ca)
#pragma unroll
      for (int cb = 0; cb < 2; ++cb)
#pragma unroll
        for (int cc = 0; cc < 2; ++cc) {
          float w = wx[ca] * wy[cb] * wz[cc];
          int tap = cbase + ca * 16 + cb * 4 + cc;
          int bb = vb + tap;
#pragma unroll
          for (int j = 0; j < 8; ++j)
            atomicAdd(&acc[bb + j * 64], w * fv[j]);
        }
  }
  __syncthreads();

  // ---- phase 2: [16 x 1024] x [1024 x 32] bf16 MFMA ----
  // wave wid owns kchunks [wid*4, wid*4+4), computes BOTH ntiles (A read once)
  int wid = tid >> 6, lane = tid & 63;
  int vrow = lane & 15, q = lane >> 4;
  f32x4 D0 = {0.f, 0.f, 0.f, 0.f};
  f32x4 D1 = {0.f, 0.f, 0.f, 0.f};
#pragma unroll
  for (int kc = 0; kc < 4; ++kc) {
    int kchunk = wid * 4 + kc;
    const f32x4* ap = (const f32x4*)&acc[vrow * ACC_STRIDE + kchunk * 32 + q * 8];
    f32x4 a0 = ap[0], a1 = ap[1];
    bf16x8 af;
    af[0] = (__bf16)a0[0]; af[1] = (__bf16)a0[1];
    af[2] = (__bf16)a0[2]; af[3] = (__bf16)a0[3];
    af[4] = (__bf16)a1[0]; af[5] = (__bf16)a1[1];
    af[6] = (__bf16)a1[2]; af[7] = (__bf16)a1[3];
    bf16x8 b0 = *(const bf16x8*)(wsB + ((kchunk * 2 + 0) * 64 + lane) * 8);
    bf16x8 b1 = *(const bf16x8*)(wsB + ((kchunk * 2 + 1) * 64 + lane) * 8);
    D0 = __builtin_amdgcn_mfma_f32_16x16x32_bf16(af, b0, D0, 0, 0, 0);
    D1 = __builtin_amdgcn_mfma_f32_16x16x32_bf16(af, b1, D1, 0, 0, 0);
  }
  __syncthreads();  // all acc reads done; alias acc as reduction buffer
  float* red = acc;
  *(f32x4*)&red[((wid * 2 + 0) * 64 + lane) * 4] = D0;
  *(f32x4*)&red[((wid * 2 + 1) * 64 + lane) * 4] = D1;
  __syncthreads();

  // epilogue: 512 threads = 16 voxels x 32 cols
  int vv = tid >> 5, col = tid & 31;
  int nt = col >> 4, c16 = col & 15;
  int qq = vv >> 2, r = vv & 3;
  int lane2 = qq * 16 + c16;
  float sacc = 0.f;
#pragma unroll
  for (int w = 0; w < 8; ++w) sacc += red[((w * 2 + nt) * 64 + lane2) * 4 + r];
  float den = denS[vv];
  den = (den != 0.f) ? den : 1.f;
  float y = sacc / den + bias[col];
  out[(size_t)(vbase + vv) * COUT + col] = fmaxf(y, 0.f);
}

extern "C" void kernel_launch(void* const* d_in, const int* in_sizes, int n_in,
                              void* d_out, int out_size, void* d_ws, size_t ws_size,
                              hipStream_t stream) {
  const float* feats = (const float*)d_in[0];
  const float* inp_pts = (const float*)d_in[1];
  const float* out_pts = (const float*)d_in[2];
  const float* out_ext = (const float*)d_in[3];
  const float* scale = (const float*)d_in[4];
  const float* ndist = (const float*)d_in[5];
  const int* nidx = (const int*)d_in[6];
  const int* rsp = (const int*)d_in[7];
  const float* kern = (const float*)d_in[8];
  const float* bias = (const float*)d_in[9];
  __bf16* wsB = (__bf16*)d_ws;

  prep_kernel<<<128, 256, 0, stream>>>(kern, wsB);
  cconv_kernel<<<N_OUT / VPB, THREADS, 0, stream>>>(
      feats, inp_pts, out_pts, out_ext, scale, ndist, nidx, rsp, bias, wsB,
      (float*)d_out);
}

// Round 3
// 309.804 us; speedup vs baseline: 3.4618x; 3.4618x over previous
//
#include <hip/hip_runtime.h>
#include <stdint.h>

#define N_OUT 100000
#define CIN 16
#define COUT 32
#define VPB 16
#define THREADS 512
#define CHUNK 16

// LDS layout (dword offsets)
#define ACC_OFF 0
#define ACC_VSTRIDE 580   // dwords/voxel: 16 ch * 36 + 4 pad (bank stagger)
#define ACC_CSTRIDE 36    // dwords/channel: 64 taps * 2B = 128B -> 144B (16B-mult)
#define PSI_OFF 9280
#define PSI_VSTRIDE 196   // dwords/voxel: 16 ch * 12 + 4 pad
#define PSI_CSTRIDE 12    // dwords/channel row: 16 slots * 2B = 32B -> 48B (16B-mult)
#define REC_OFF 12416     // [16 v][16 slots][4 floats]
#define RSP_OFF 13440
#define DEN_OFF 13457
#define CMAX_OFF 13473
#define SMEM_DW 13476     // ~53.9 KB -> 3 blocks/CU

typedef __attribute__((ext_vector_type(4))) float f32x4;
typedef __attribute__((ext_vector_type(8))) __bf16 bf16x8;
typedef __attribute__((ext_vector_type(4))) __bf16 bf16x4;

__device__ __forceinline__ float clampf(float x, float lo, float hi) {
  return fminf(fmaxf(x, lo), hi);
}
__device__ __forceinline__ float hatf(float x) {
  return fmaxf(0.f, 1.f - fabsf(x));
}

// prep: kernel fp32 [64 taps][16 cin][32 cout] -> bf16 MFMA B-fragments,
// K permuted as k = cin*64 + tap. (validated in R1/R2)
__global__ void prep_kernel(const float* __restrict__ kern, __bf16* __restrict__ wsB) {
  int t = blockIdx.x * blockDim.x + threadIdx.x;  // 0..32767
  int j = t & 7;
  int lane = (t >> 3) & 63;
  int ntile = (t >> 9) & 1;
  int kchunk = t >> 10;
  int k = kchunk * 32 + (lane >> 4) * 8 + j;
  int tap = k & 63;
  int cin = k >> 6;
  int o = ntile * 16 + (lane & 15);
  wsB[t] = (__bf16)kern[(tap * CIN + cin) * COUT + o];
}

__global__ __launch_bounds__(THREADS, 6) void cconv_kernel(
    const float* __restrict__ feats, const float* __restrict__ inp_pts,
    const float* __restrict__ out_pts, const float* __restrict__ out_ext,
    const float* __restrict__ scale, const float* __restrict__ ndist,
    const int* __restrict__ nidx, const int* __restrict__ rsp,
    const float* __restrict__ bias, const __bf16* __restrict__ wsB,
    float* __restrict__ out) {
  __shared__ __align__(16) float sm[SMEM_DW];
  int* rsp_s = (int*)(sm + RSP_OFF);
  float* denS = sm + DEN_OFF;
  int* cmax_p = (int*)(sm + CMAX_OFF);

  int tid = threadIdx.x;
  int vbase = blockIdx.x * VPB;

  if (tid < VPB + 1) rsp_s[tid] = rsp[vbase + tid];
  if (tid < VPB) denS[tid] = 0.f;
  __syncthreads();
  if (tid == 0) {
    int cm = 0;
    for (int v = 0; v < VPB; ++v) cm = max(cm, rsp_s[v + 1] - rsp_s[v]);
    *cmax_p = cm;
  }
  __syncthreads();
  int cmax = *cmax_p;

  int wid = tid >> 6, lane = tid & 63;
  int q = lane >> 4, l15 = lane & 15;

  f32x4 DA[2][4] = {};  // stage-A accumulators: 2 voxels x 4 tap-tiles

  for (int c0 = 0; c0 < cmax; c0 += CHUNK) {
    // ---- staging: 256 threads = 16 voxels x 16 slots ----
    if (tid < 256) {
      int v = tid >> 4, slot = tid & 15;
      int cnt = rsp_s[v + 1] - rsp_s[v];
      bool valid = (c0 + slot) < cnt;
      float tx = 0.f, ty = 0.f, tz = 0.f, imp = 0.f;
      __bf16 psi[CIN];
      if (valid) {
        int e = rsp_s[v] + c0 + slot;
        int n = vbase + v;
        int nbr = nidx[e];
        float dsq = ndist[e];
        float p6 = 1.f - dsq;
        p6 = p6 * p6 * p6;
        p6 = clampf(p6, 0.f, 1.f);
        imp = scale[e] * p6;
        float inv = 2.f / out_ext[n];
        float rx = (inp_pts[nbr * 3 + 0] - out_pts[n * 3 + 0]) * inv;
        float ry = (inp_pts[nbr * 3 + 1] - out_pts[n * 3 + 1]) * inv;
        float rz = (inp_pts[nbr * 3 + 2] - out_pts[n * 3 + 2]) * inv;
        float l2 = sqrtf(rx * rx + ry * ry + rz * rz);
        float linf = fmaxf(fabsf(rx), fmaxf(fabsf(ry), fabsf(rz)));
        float s = (linf > 0.f) ? (l2 / fmaxf(linf, 1e-12f)) : 0.f;
        float qx = clampf(rx * s, -1.f, 1.f);
        float qy = clampf(ry * s, -1.f, 1.f);
        float qz = clampf(rz * s, -1.f, 1.f);
        tx = (qx + 1.f) * 1.5f;
        ty = (qy + 1.f) * 1.5f;
        tz = (qz + 1.f) * 1.5f;
        const f32x4* fp = (const f32x4*)(feats + (size_t)nbr * CIN);
        f32x4 f0 = fp[0], f1 = fp[1], f2 = fp[2], f3 = fp[3];
        psi[0] = (__bf16)(imp * f0[0]);  psi[1] = (__bf16)(imp * f0[1]);
        psi[2] = (__bf16)(imp * f0[2]);  psi[3] = (__bf16)(imp * f0[3]);
        psi[4] = (__bf16)(imp * f1[0]);  psi[5] = (__bf16)(imp * f1[1]);
        psi[6] = (__bf16)(imp * f1[2]);  psi[7] = (__bf16)(imp * f1[3]);
        psi[8] = (__bf16)(imp * f2[0]);  psi[9] = (__bf16)(imp * f2[1]);
        psi[10] = (__bf16)(imp * f2[2]); psi[11] = (__bf16)(imp * f2[3]);
        psi[12] = (__bf16)(imp * f3[0]); psi[13] = (__bf16)(imp * f3[1]);
        psi[14] = (__bf16)(imp * f3[2]); psi[15] = (__bf16)(imp * f3[3]);
      } else {
#pragma unroll
        for (int c = 0; c < CIN; ++c) psi[c] = (__bf16)0.f;
      }
      f32x4 r4 = {tx, ty, tz, imp};
      *(f32x4*)(sm + REC_OFF + (v * 16 + slot) * 4) = r4;
      __bf16* pt = (__bf16*)(sm + PSI_OFF + v * PSI_VSTRIDE);
#pragma unroll
      for (int c = 0; c < CIN; ++c) pt[c * (PSI_CSTRIDE * 2) + slot] = psi[c];
      // denominator: reduce imp over the 16 slots of this voxel (one 16-lane group)
      float r = imp;
      r += __shfl_xor(r, 1);
      r += __shfl_xor(r, 2);
      r += __shfl_xor(r, 4);
      r += __shfl_xor(r, 8);
      if (slot == 0) denS[v] += r;
    }
    __syncthreads();
    // ---- stage A: acc[v][64 taps][16 ch] = W * psi via MFMA, wave -> 2 voxels
#pragma unroll
    for (int vi = 0; vi < 2; ++vi) {
      int v = wid * 2 + vi;
      int cnt = rsp_s[v + 1] - rsp_s[v];
      int m_v = min(cnt - c0, CHUNK);
      if (m_v <= 0) continue;
      int qc = (q < 2) ? q : 1;  // q>=2 lanes: A=0, any finite B is fine
      bf16x8 bfrag = *(const bf16x8*)(
          (const __bf16*)(sm + PSI_OFF + v * PSI_VSTRIDE + l15 * PSI_CSTRIDE) + qc * 8);
      bf16x8 af0, af1, af2, af3;
      float m1 = (float)(l15 >> 2);  // iy of this lane's taps
      float m0 = (float)(l15 & 3);   // iz
#pragma unroll
      for (int j = 0; j < 8; ++j) {
        int s = q * 8 + j;
        float w0 = 0.f, w1 = 0.f, w2 = 0.f, w3 = 0.f;
        if (s < m_v) {
          f32x4 r4 = *(const f32x4*)(sm + REC_OFF + (v * 16 + s) * 4);
          float wyz = hatf(r4[1] - m1) * hatf(r4[2] - m0);
          w0 = hatf(r4[0]) * wyz;
          w1 = hatf(r4[0] - 1.f) * wyz;
          w2 = hatf(r4[0] - 2.f) * wyz;
          w3 = hatf(r4[0] - 3.f) * wyz;
        }
        af0[j] = (__bf16)w0; af1[j] = (__bf16)w1;
        af2[j] = (__bf16)w2; af3[j] = (__bf16)w3;
      }
      DA[vi][0] = __builtin_amdgcn_mfma_f32_16x16x32_bf16(af0, bfrag, DA[vi][0], 0, 0, 0);
      DA[vi][1] = __builtin_amdgcn_mfma_f32_16x16x32_bf16(af1, bfrag, DA[vi][1], 0, 0, 0);
      DA[vi][2] = __builtin_amdgcn_mfma_f32_16x16x32_bf16(af2, bfrag, DA[vi][2], 0, 0, 0);
      DA[vi][3] = __builtin_amdgcn_mfma_f32_16x16x32_bf16(af3, bfrag, DA[vi][3], 0, 0, 0);
    }
    __syncthreads();
  }

  // ---- write stage-A C (taps t*16+q*4+r, ch=l15) to acc as bf16 ----
#pragma unroll
  for (int vi = 0; vi < 2; ++vi) {
    int v = wid * 2 + vi;
    __bf16* ab = (__bf16*)(sm + ACC_OFF + v * ACC_VSTRIDE + l15 * ACC_CSTRIDE);
#pragma unroll
    for (int t = 0; t < 4; ++t) {
      bf16x4 pk;
      pk[0] = (__bf16)DA[vi][t][0]; pk[1] = (__bf16)DA[vi][t][1];
      pk[2] = (__bf16)DA[vi][t][2]; pk[3] = (__bf16)DA[vi][t][3];
      *(bf16x4*)(ab + t * 16 + q * 4) = pk;
    }
  }
  __syncthreads();

  // ---- stage B: [16 x 1024] x [1024 x 32], k = ch*64 + tap ----
  f32x4 D0 = {0.f, 0.f, 0.f, 0.f};
  f32x4 D1 = {0.f, 0.f, 0.f, 0.f};
  const __bf16* accv = (const __bf16*)(sm + ACC_OFF + l15 * ACC_VSTRIDE);
#pragma unroll
  for (int kc = 0; kc < 4; ++kc) {
    int kchunk = wid * 4 + kc;
    int c = kchunk >> 1;
    int tap = (kchunk & 1) * 32 + q * 8;
    bf16x8 af = *(const bf16x8*)(accv + c * (ACC_CSTRIDE * 2) + tap);
    bf16x8 b0 = *(const bf16x8*)(wsB + ((kchunk * 2 + 0) * 64 + lane) * 8);
    bf16x8 b1 = *(const bf16x8*)(wsB + ((kchunk * 2 + 1) * 64 + lane) * 8);
    D0 = __builtin_amdgcn_mfma_f32_16x16x32_bf16(af, b0, D0, 0, 0, 0);
    D1 = __builtin_amdgcn_mfma_f32_16x16x32_bf16(af, b1, D1, 0, 0, 0);
  }
  __syncthreads();  // all acc reads done; alias acc region as reduction buffer
  float* red = sm + ACC_OFF;
  *(f32x4*)&red[((wid * 2 + 0) * 64 + lane) * 4] = D0;
  *(f32x4*)&red[((wid * 2 + 1) * 64 + lane) * 4] = D1;
  __syncthreads();

  // ---- epilogue: 512 threads = 16 voxels x 32 cols (validated in R2) ----
  int vv = tid >> 5, col = tid & 31;
  int nt = col >> 4, c16 = col & 15;
  int qq = vv >> 2, r = vv & 3;
  int lane2 = qq * 16 + c16;
  float sacc = 0.f;
#pragma unroll
  for (int w = 0; w < 8; ++w) sacc += red[((w * 2 + nt) * 64 + lane2) * 4 + r];
  float den = denS[vv];
  den = (den != 0.f) ? den : 1.f;
  float y = sacc / den + bias[col];
  out[(size_t)(vbase + vv) * COUT + col] = fmaxf(y, 0.f);
}

extern "C" void kernel_launch(void* const* d_in, const int* in_sizes, int n_in,
                              void* d_out, int out_size, void* d_ws, size_t ws_size,
                              hipStream_t stream) {
  const float* feats = (const float*)d_in[0];
  const float* inp_pts = (const float*)d_in[1];
  const float* out_pts = (const float*)d_in[2];
  const float* out_ext = (const float*)d_in[3];
  const float* scale = (const float*)d_in[4];
  const float* ndist = (const float*)d_in[5];
  const int* nidx = (const int*)d_in[6];
  const int* rsp = (const int*)d_in[7];
  const float* kern = (const float*)d_in[8];
  const float* bias = (const float*)d_in[9];
  __bf16* wsB = (__bf16*)d_ws;

  prep_kernel<<<128, 256, 0, stream>>>(kern, wsB);
  cconv_kernel<<<N_OUT / VPB, THREADS, 0, stream>>>(
      feats, inp_pts, out_pts, out_ext, scale, ndist, nidx, rsp, bias, wsB,
      (float*)d_out);
}

// Round 4
// 185.819 us; speedup vs baseline: 5.7717x; 1.6672x over previous
//
#include <hip/hip_runtime.h>
#include <stdint.h>

#define N_OUT 100000
#define CIN 16
#define COUT 32
#define VPB 16
#define THREADS 512
#define CHUNK 16

// LDS layout (dword offsets)
#define ACC_OFF 0
#define ACC_VSTRIDE 580   // dwords/voxel: 16 ch * 36 + 4 pad (bank stagger)
#define ACC_CSTRIDE 36    // dwords/channel: 64 taps * 2B = 128B -> 144B (16B-mult)
#define PSI_OFF 9280
#define PSI_VSTRIDE 196   // dwords/voxel: 16 ch * 12 + 4 pad
#define PSI_CSTRIDE 12    // dwords/channel row: 16 slots * 2B = 32B -> 48B (16B-mult)
#define REC_OFF 12416     // [16 v][16 slots][4 floats]
#define RSP_OFF 13440
#define DEN_OFF 13457
#define CMAX_OFF 13473
#define SMEM_DW 13476     // ~53.9 KB -> 3 blocks/CU

typedef __attribute__((ext_vector_type(4))) float f32x4;
typedef __attribute__((ext_vector_type(8))) __bf16 bf16x8;
typedef __attribute__((ext_vector_type(4))) __bf16 bf16x4;

__device__ __forceinline__ float clampf(float x, float lo, float hi) {
  return fminf(fmaxf(x, lo), hi);
}
__device__ __forceinline__ float hatf(float x) {
  return fmaxf(0.f, 1.f - fabsf(x));
}

// prep: kernel fp32 [64 taps][16 cin][32 cout] -> bf16 MFMA B-fragments,
// K permuted as k = cin*64 + tap. (validated R1-R3)
__global__ void prep_kernel(const float* __restrict__ kern, __bf16* __restrict__ wsB) {
  int t = blockIdx.x * blockDim.x + threadIdx.x;  // 0..32767
  int j = t & 7;
  int lane = (t >> 3) & 63;
  int ntile = (t >> 9) & 1;
  int kchunk = t >> 10;
  int k = kchunk * 32 + (lane >> 4) * 8 + j;
  int tap = k & 63;
  int cin = k >> 6;
  int o = ntile * 16 + (lane & 15);
  wsB[t] = (__bf16)kern[(tap * CIN + cin) * COUT + o];
}

// launch_bounds 2nd arg acts as min BLOCKS/CU (empirical: R2 (512,4)->52 VGPR,
// R3 (512,6)->40 VGPR + catastrophic spill). 3 blocks * 8 waves / 4 SIMD =
// 6 waves/EU -> 85-VGPR cap; kernel needs ~80. LDS 54KB also allows 3 blocks.
__global__ __launch_bounds__(THREADS, 3) void cconv_kernel(
    const float* __restrict__ feats, const float* __restrict__ inp_pts,
    const float* __restrict__ out_pts, const float* __restrict__ out_ext,
    const float* __restrict__ scale, const float* __restrict__ ndist,
    const int* __restrict__ nidx, const int* __restrict__ rsp,
    const float* __restrict__ bias, const __bf16* __restrict__ wsB,
    float* __restrict__ out) {
  __shared__ __align__(16) float sm[SMEM_DW];
  int* rsp_s = (int*)(sm + RSP_OFF);
  float* denS = sm + DEN_OFF;
  int* cmax_p = (int*)(sm + CMAX_OFF);

  int tid = threadIdx.x;
  int vbase = blockIdx.x * VPB;

  if (tid < VPB + 1) rsp_s[tid] = rsp[vbase + tid];
  if (tid < VPB) denS[tid] = 0.f;
  __syncthreads();
  if (tid == 0) {
    int cm = 0;
    for (int v = 0; v < VPB; ++v) cm = max(cm, rsp_s[v + 1] - rsp_s[v]);
    *cmax_p = cm;
  }
  __syncthreads();
  int cmax = *cmax_p;

  int wid = tid >> 6, lane = tid & 63;
  int q = lane >> 4, l15 = lane & 15;

  f32x4 DA[2][4] = {};  // stage-A accumulators: 2 voxels x 4 tap-tiles

  for (int c0 = 0; c0 < cmax; c0 += CHUNK) {
    // ---- staging: 256 threads = 16 voxels x 16 slots ----
    if (tid < 256) {
      int v = tid >> 4, slot = tid & 15;
      int cnt = rsp_s[v + 1] - rsp_s[v];
      bool valid = (c0 + slot) < cnt;
      float tx = 0.f, ty = 0.f, tz = 0.f, imp = 0.f;
      __bf16* pt = (__bf16*)(sm + PSI_OFF + v * PSI_VSTRIDE);
      if (valid) {
        int e = rsp_s[v] + c0 + slot;
        int n = vbase + v;
        int nbr = nidx[e];
        float dsq = ndist[e];
        float p6 = 1.f - dsq;
        p6 = p6 * p6 * p6;
        p6 = clampf(p6, 0.f, 1.f);
        imp = scale[e] * p6;
        float inv = 2.f / out_ext[n];
        float rx = (inp_pts[nbr * 3 + 0] - out_pts[n * 3 + 0]) * inv;
        float ry = (inp_pts[nbr * 3 + 1] - out_pts[n * 3 + 1]) * inv;
        float rz = (inp_pts[nbr * 3 + 2] - out_pts[n * 3 + 2]) * inv;
        float l2 = sqrtf(rx * rx + ry * ry + rz * rz);
        float linf = fmaxf(fabsf(rx), fmaxf(fabsf(ry), fabsf(rz)));
        float s = (linf > 0.f) ? (l2 / fmaxf(linf, 1e-12f)) : 0.f;
        float qx = clampf(rx * s, -1.f, 1.f);
        float qy = clampf(ry * s, -1.f, 1.f);
        float qz = clampf(rz * s, -1.f, 1.f);
        tx = (qx + 1.f) * 1.5f;
        ty = (qy + 1.f) * 1.5f;
        tz = (qz + 1.f) * 1.5f;
        // psi in 4-channel chunks to keep register liveness low
        const f32x4* fp = (const f32x4*)(feats + (size_t)nbr * CIN);
#pragma unroll
        for (int g = 0; g < 4; ++g) {
          f32x4 fg = fp[g];
#pragma unroll
          for (int c4 = 0; c4 < 4; ++c4)
            pt[(g * 4 + c4) * (PSI_CSTRIDE * 2) + slot] = (__bf16)(imp * fg[c4]);
        }
      } else {
#pragma unroll
        for (int c = 0; c < CIN; ++c) pt[c * (PSI_CSTRIDE * 2) + slot] = (__bf16)0.f;
      }
      f32x4 r4 = {tx, ty, tz, imp};
      *(f32x4*)(sm + REC_OFF + (v * 16 + slot) * 4) = r4;
      // denominator: reduce imp over the 16 slots of this voxel
      float r = imp;
      r += __shfl_xor(r, 1);
      r += __shfl_xor(r, 2);
      r += __shfl_xor(r, 4);
      r += __shfl_xor(r, 8);
      if (slot == 0) denS[v] += r;
    }
    __syncthreads();
    // ---- stage A: acc[v][64 taps][16 ch] = W * psi via MFMA, wave -> 2 voxels
#pragma unroll
    for (int vi = 0; vi < 2; ++vi) {
      int v = wid * 2 + vi;
      int cnt = rsp_s[v + 1] - rsp_s[v];
      int m_v = min(cnt - c0, CHUNK);
      if (m_v <= 0) continue;
      int qc = (q < 2) ? q : 1;  // q>=2 lanes: A=0, any finite B is fine
      bf16x8 bfrag = *(const bf16x8*)(
          (const __bf16*)(sm + PSI_OFF + v * PSI_VSTRIDE + l15 * PSI_CSTRIDE) + qc * 8);
      bf16x8 af0, af1, af2, af3;
      float m1 = (float)(l15 >> 2);  // iy of this lane's taps
      float m0 = (float)(l15 & 3);   // iz
#pragma unroll
      for (int j = 0; j < 8; ++j) {
        int s = q * 8 + j;
        float w0 = 0.f, w1 = 0.f, w2 = 0.f, w3 = 0.f;
        if (s < m_v) {
          f32x4 r4 = *(const f32x4*)(sm + REC_OFF + (v * 16 + s) * 4);
          float wyz = hatf(r4[1] - m1) * hatf(r4[2] - m0);
          w0 = hatf(r4[0]) * wyz;
          w1 = hatf(r4[0] - 1.f) * wyz;
          w2 = hatf(r4[0] - 2.f) * wyz;
          w3 = hatf(r4[0] - 3.f) * wyz;
        }
        af0[j] = (__bf16)w0; af1[j] = (__bf16)w1;
        af2[j] = (__bf16)w2; af3[j] = (__bf16)w3;
      }
      DA[vi][0] = __builtin_amdgcn_mfma_f32_16x16x32_bf16(af0, bfrag, DA[vi][0], 0, 0, 0);
      DA[vi][1] = __builtin_amdgcn_mfma_f32_16x16x32_bf16(af1, bfrag, DA[vi][1], 0, 0, 0);
      DA[vi][2] = __builtin_amdgcn_mfma_f32_16x16x32_bf16(af2, bfrag, DA[vi][2], 0, 0, 0);
      DA[vi][3] = __builtin_amdgcn_mfma_f32_16x16x32_bf16(af3, bfrag, DA[vi][3], 0, 0, 0);
    }
    __syncthreads();
  }

  // ---- write stage-A C (taps t*16+q*4+r, ch=l15) to acc as bf16 ----
#pragma unroll
  for (int vi = 0; vi < 2; ++vi) {
    int v = wid * 2 + vi;
    __bf16* ab = (__bf16*)(sm + ACC_OFF + v * ACC_VSTRIDE + l15 * ACC_CSTRIDE);
#pragma unroll
    for (int t = 0; t < 4; ++t) {
      bf16x4 pk;
      pk[0] = (__bf16)DA[vi][t][0]; pk[1] = (__bf16)DA[vi][t][1];
      pk[2] = (__bf16)DA[vi][t][2]; pk[3] = (__bf16)DA[vi][t][3];
      *(bf16x4*)(ab + t * 16 + q * 4) = pk;
    }
  }
  __syncthreads();

  // ---- stage B: [16 x 1024] x [1024 x 32], k = ch*64 + tap ----
  f32x4 D0 = {0.f, 0.f, 0.f, 0.f};
  f32x4 D1 = {0.f, 0.f, 0.f, 0.f};
  const __bf16* accv = (const __bf16*)(sm + ACC_OFF + l15 * ACC_VSTRIDE);
#pragma unroll
  for (int kc = 0; kc < 4; ++kc) {
    int kchunk = wid * 4 + kc;
    int c = kchunk >> 1;
    int tap = (kchunk & 1) * 32 + q * 8;
    bf16x8 af = *(const bf16x8*)(accv + c * (ACC_CSTRIDE * 2) + tap);
    bf16x8 b0 = *(const bf16x8*)(wsB + ((kchunk * 2 + 0) * 64 + lane) * 8);
    bf16x8 b1 = *(const bf16x8*)(wsB + ((kchunk * 2 + 1) * 64 + lane) * 8);
    D0 = __builtin_amdgcn_mfma_f32_16x16x32_bf16(af, b0, D0, 0, 0, 0);
    D1 = __builtin_amdgcn_mfma_f32_16x16x32_bf16(af, b1, D1, 0, 0, 0);
  }
  __syncthreads();  // all acc reads done; alias acc region as reduction buffer
  float* red = sm + ACC_OFF;
  *(f32x4*)&red[((wid * 2 + 0) * 64 + lane) * 4] = D0;
  *(f32x4*)&red[((wid * 2 + 1) * 64 + lane) * 4] = D1;
  __syncthreads();

  // ---- epilogue: 512 threads = 16 voxels x 32 cols ----
  int vv = tid >> 5, col = tid & 31;
  int nt = col >> 4, c16 = col & 15;
  int qq = vv >> 2, r = vv & 3;
  int lane2 = qq * 16 + c16;
  float sacc = 0.f;
#pragma unroll
  for (int w = 0; w < 8; ++w) sacc += red[((w * 2 + nt) * 64 + lane2) * 4 + r];
  float den = denS[vv];
  den = (den != 0.f) ? den : 1.f;
  float y = sacc / den + bias[col];
  out[(size_t)(vbase + vv) * COUT + col] = fmaxf(y, 0.f);
}

extern "C" void kernel_launch(void* const* d_in, const int* in_sizes, int n_in,
                              void* d_out, int out_size, void* d_ws, size_t ws_size,
                              hipStream_t stream) {
  const float* feats = (const float*)d_in[0];
  const float* inp_pts = (const float*)d_in[1];
  const float* out_pts = (const float*)d_in[2];
  const float* out_ext = (const float*)d_in[3];
  const float* scale = (const float*)d_in[4];
  const float* ndist = (const float*)d_in[5];
  const int* nidx = (const int*)d_in[6];
  const int* rsp = (const int*)d_in[7];
  const float* kern = (const float*)d_in[8];
  const float* bias = (const float*)d_in[9];
  __bf16* wsB = (__bf16*)d_ws;

  prep_kernel<<<128, 256, 0, stream>>>(kern, wsB);
  cconv_kernel<<<N_OUT / VPB, THREADS, 0, stream>>>(
      feats, inp_pts, out_pts, out_ext, scale, ndist, nidx, rsp, bias, wsB,
      (float*)d_out);
}

// Round 6
// 165.485 us; speedup vs baseline: 6.4809x; 1.1229x over previous
//
#include <hip/hip_runtime.h>
#include <stdint.h>

#define N_OUT 100000
#define CIN 16
#define COUT 32
#define VPB 16
#define THREADS 512
#define CHUNK 16

// LDS layout (dword offsets)
#define ACC_OFF 0
#define ACC_VSTRIDE 580   // dwords/voxel: 16 ch * 36 + 4 pad
#define ACC_CSTRIDE 36    // dwords/channel: 64 taps * 2B -> 144B
#define PSI_OFF 9280
#define PSI_VSTRIDE 200   // 16 ch * 12 + 8 pad; 200%32==8 -> voxel bank-octet spread
#define PSI_CSTRIDE 12    // dwords/channel row: 16 slots * 2B -> 48B
#define REC_OFF 12480     // [16 v][16 slots][4 floats]
#define RSP_OFF 13504
#define DEN_OFF 13521
#define CMAX_OFF 13537
#define SMEM_DW 13540     // ~54.2 KB -> 3 blocks/CU

typedef __attribute__((ext_vector_type(4))) float f32x4;
typedef __attribute__((ext_vector_type(8))) __bf16 bf16x8;
typedef __attribute__((ext_vector_type(4))) __bf16 bf16x4;
typedef __attribute__((ext_vector_type(4))) short s16x4;  // renamed: short4 is a HIP type

__device__ __forceinline__ float clampf(float x, float lo, float hi) {
  return fminf(fmaxf(x, lo), hi);
}
__device__ __forceinline__ float hatf(float x) {
  return fmaxf(0.f, 1.f - fabsf(x));
}

// prep: kernel fp32 [64 taps][16 cin][32 cout] -> bf16 MFMA B-fragments,
// K permuted as k = cin*64 + tap. (validated R1-R4; stage B only)
__global__ void prep_kernel(const float* __restrict__ kern, __bf16* __restrict__ wsB) {
  int t = blockIdx.x * blockDim.x + threadIdx.x;  // 0..32767
  int j = t & 7;
  int lane = (t >> 3) & 63;
  int ntile = (t >> 9) & 1;
  int kchunk = t >> 10;
  int k = kchunk * 32 + (lane >> 4) * 8 + j;
  int tap = k & 63;
  int cin = k >> 6;
  int o = ntile * 16 + (lane & 15);
  wsB[t] = (__bf16)kern[(tap * CIN + cin) * COUT + o];
}

// launch_bounds 2nd arg = min BLOCKS/CU (empirical R2/R3/R4). 3 blocks ->
// 6 waves/EU -> ~85-VGPR cap; R4 measured 64 VGPR, no spill.
__global__ __launch_bounds__(THREADS, 3) void cconv_kernel(
    const float* __restrict__ feats, const float* __restrict__ inp_pts,
    const float* __restrict__ out_pts, const float* __restrict__ out_ext,
    const float* __restrict__ scale, const float* __restrict__ ndist,
    const int* __restrict__ nidx, const int* __restrict__ rsp,
    const float* __restrict__ bias, const __bf16* __restrict__ wsB,
    float* __restrict__ out) {
  __shared__ __align__(16) float sm[SMEM_DW];
  int* rsp_s = (int*)(sm + RSP_OFF);
  float* denS = sm + DEN_OFF;
  int* cmax_p = (int*)(sm + CMAX_OFF);

  int tid = threadIdx.x;
  int vbase = blockIdx.x * VPB;

  if (tid < VPB + 1) rsp_s[tid] = rsp[vbase + tid];
  if (tid < VPB) denS[tid] = 0.f;
  __syncthreads();
  if (tid < VPB) {
    int cm = rsp_s[tid + 1] - rsp_s[tid];
    cm = max(cm, __shfl_xor(cm, 1));
    cm = max(cm, __shfl_xor(cm, 2));
    cm = max(cm, __shfl_xor(cm, 4));
    cm = max(cm, __shfl_xor(cm, 8));
    if (tid == 0) *cmax_p = cm;
  }
  __syncthreads();
  int cmax = *cmax_p;

  int wid = tid >> 6, lane = tid & 63;
  int q = lane >> 4, l15 = lane & 15;

  f32x4 DA[2][4] = {};  // stage-A accumulators: 2 voxels x 4 tap-tiles

  for (int c0 = 0; c0 < cmax; c0 += CHUNK) {
    // ---- staging: 256 threads = 16 voxels x 16 slots ----
    if (tid < 256) {
      int v = tid >> 4, slot = tid & 15;
      int cnt = rsp_s[v + 1] - rsp_s[v];
      bool valid = (c0 + slot) < cnt;
      float tx = 0.f, ty = 0.f, tz = 0.f, imp = 0.f;
      __bf16* pt = (__bf16*)(sm + PSI_OFF + v * PSI_VSTRIDE);
      if (valid) {
        int e = rsp_s[v] + c0 + slot;
        int n = vbase + v;
        int nbr = nidx[e];
        float dsq = ndist[e];
        float p6 = 1.f - dsq;
        p6 = p6 * p6 * p6;
        p6 = clampf(p6, 0.f, 1.f);
        imp = scale[e] * p6;
        float inv = 2.f * __builtin_amdgcn_rcpf(out_ext[n]);
        float rx = (inp_pts[nbr * 3 + 0] - out_pts[n * 3 + 0]) * inv;
        float ry = (inp_pts[nbr * 3 + 1] - out_pts[n * 3 + 1]) * inv;
        float rz = (inp_pts[nbr * 3 + 2] - out_pts[n * 3 + 2]) * inv;
        float l2 = __builtin_amdgcn_sqrtf(rx * rx + ry * ry + rz * rz);
        float linf = fmaxf(fabsf(rx), fmaxf(fabsf(ry), fabsf(rz)));
        float s = (linf > 0.f)
                      ? (l2 * __builtin_amdgcn_rcpf(fmaxf(linf, 1e-12f)))
                      : 0.f;
        float qx = clampf(rx * s, -1.f, 1.f);
        float qy = clampf(ry * s, -1.f, 1.f);
        float qz = clampf(rz * s, -1.f, 1.f);
        tx = (qx + 1.f) * 1.5f;
        ty = (qy + 1.f) * 1.5f;
        tz = (qz + 1.f) * 1.5f;
        const f32x4* fp = (const f32x4*)(feats + (size_t)nbr * CIN);
#pragma unroll
        for (int g = 0; g < 4; ++g) {
          f32x4 fg = fp[g];
#pragma unroll
          for (int c4 = 0; c4 < 4; ++c4)
            pt[(g * 4 + c4) * (PSI_CSTRIDE * 2) + slot] = (__bf16)(imp * fg[c4]);
        }
      } else {
#pragma unroll
        for (int c = 0; c < CIN; ++c) pt[c * (PSI_CSTRIDE * 2) + slot] = (__bf16)0.f;
      }
      f32x4 r4 = {tx, ty, tz, imp};
      *(f32x4*)(sm + REC_OFF + (v * 16 + slot) * 4) = r4;
      float r = imp;
      r += __shfl_xor(r, 1);
      r += __shfl_xor(r, 2);
      r += __shfl_xor(r, 4);
      r += __shfl_xor(r, 8);
      if (slot == 0) denS[v] += r;
    }
    __syncthreads();
    // ---- stage A: acc[v][64 taps][16 ch] = W * psi, wave -> 2 voxels ----
    // Invalid slots have psi==0, so W may be arbitrary (finite) there: no guard.
#pragma unroll
    for (int vi = 0; vi < 2; ++vi) {
      int v = wid * 2 + vi;
      float m1 = (float)(l15 >> 2);  // iy of this lane's taps
      float m0 = (float)(l15 & 3);   // iz
#if __has_builtin(__builtin_amdgcn_mfma_f32_16x16x16bf16_1k)
      // K=16: slot = q*4+j, j=0..3. B-frag: psi[ch=l15][slot q*4..+3] (one b64).
      s16x4 bs = *(const s16x4*)(
          (const __bf16*)(sm + PSI_OFF + v * PSI_VSTRIDE) + l15 * (PSI_CSTRIDE * 2) + q * 4);
      float w[4][4];
#pragma unroll
      for (int j = 0; j < 4; ++j) {
        f32x4 r4 = *(const f32x4*)(sm + REC_OFF + (v * 16 + q * 4 + j) * 4);
        float wyz = hatf(r4[1] - m1) * hatf(r4[2] - m0);
        w[0][j] = hatf(r4[0]) * wyz;
        w[1][j] = hatf(r4[0] - 1.f) * wyz;
        w[2][j] = hatf(r4[0] - 2.f) * wyz;
        w[3][j] = hatf(r4[0] - 3.f) * wyz;
      }
#pragma unroll
      for (int t = 0; t < 4; ++t) {
        bf16x4 af;
        af[0] = (__bf16)w[t][0]; af[1] = (__bf16)w[t][1];
        af[2] = (__bf16)w[t][2]; af[3] = (__bf16)w[t][3];
        DA[vi][t] = __builtin_amdgcn_mfma_f32_16x16x16bf16_1k(
            *(s16x4*)&af, bs, DA[vi][t], 0, 0, 0);
      }
#else
      // fallback: K=32 with zero-padded upper half (R4 structure)
      int qc = (q < 2) ? q : 1;
      bf16x8 bfrag = *(const bf16x8*)(
          (const __bf16*)(sm + PSI_OFF + v * PSI_VSTRIDE) + l15 * (PSI_CSTRIDE * 2) + qc * 8);
      bf16x8 af0, af1, af2, af3;
#pragma unroll
      for (int j = 0; j < 8; ++j) {
        int s = q * 8 + j;
        float w0 = 0.f, w1 = 0.f, w2 = 0.f, w3 = 0.f;
        if (s < 16) {
          f32x4 r4 = *(const f32x4*)(sm + REC_OFF + (v * 16 + s) * 4);
          float wyz = hatf(r4[1] - m1) * hatf(r4[2] - m0);
          w0 = hatf(r4[0]) * wyz;
          w1 = hatf(r4[0] - 1.f) * wyz;
          w2 = hatf(r4[0] - 2.f) * wyz;
          w3 = hatf(r4[0] - 3.f) * wyz;
        }
        af0[j] = (__bf16)w0; af1[j] = (__bf16)w1;
        af2[j] = (__bf16)w2; af3[j] = (__bf16)w3;
      }
      DA[vi][0] = __builtin_amdgcn_mfma_f32_16x16x32_bf16(af0, bfrag, DA[vi][0], 0, 0, 0);
      DA[vi][1] = __builtin_amdgcn_mfma_f32_16x16x32_bf16(af1, bfrag, DA[vi][1], 0, 0, 0);
      DA[vi][2] = __builtin_amdgcn_mfma_f32_16x16x32_bf16(af2, bfrag, DA[vi][2], 0, 0, 0);
      DA[vi][3] = __builtin_amdgcn_mfma_f32_16x16x32_bf16(af3, bfrag, DA[vi][3], 0, 0, 0);
#endif
    }
    __syncthreads();
  }

  // ---- write stage-A C (taps t*16+q*4+r, ch=l15) to acc as bf16 ----
#pragma unroll
  for (int vi = 0; vi < 2; ++vi) {
    int v = wid * 2 + vi;
    __bf16* ab = (__bf16*)(sm + ACC_OFF + v * ACC_VSTRIDE + l15 * ACC_CSTRIDE);
#pragma unroll
    for (int t = 0; t < 4; ++t) {
      bf16x4 pk;
      pk[0] = (__bf16)DA[vi][t][0]; pk[1] = (__bf16)DA[vi][t][1];
      pk[2] = (__bf16)DA[vi][t][2]; pk[3] = (__bf16)DA[vi][t][3];
      *(bf16x4*)(ab + t * 16 + q * 4) = pk;
    }
  }
  __syncthreads();

  // ---- stage B: [16 x 1024] x [1024 x 32], k = ch*64 + tap ----
  f32x4 D0 = {0.f, 0.f, 0.f, 0.f};
  f32x4 D1 = {0.f, 0.f, 0.f, 0.f};
  const __bf16* accv = (const __bf16*)(sm + ACC_OFF + l15 * ACC_VSTRIDE);
#pragma unroll
  for (int kc = 0; kc < 4; ++kc) {
    int kchunk = wid * 4 + kc;
    int c = kchunk >> 1;
    int tap = (kchunk & 1) * 32 + q * 8;
    bf16x8 af = *(const bf16x8*)(accv + c * (ACC_CSTRIDE * 2) + tap);
    bf16x8 b0 = *(const bf16x8*)(wsB + ((kchunk * 2 + 0) * 64 + lane) * 8);
    bf16x8 b1 = *(const bf16x8*)(wsB + ((kchunk * 2 + 1) * 64 + lane) * 8);
    D0 = __builtin_amdgcn_mfma_f32_16x16x32_bf16(af, b0, D0, 0, 0, 0);
    D1 = __builtin_amdgcn_mfma_f32_16x16x32_bf16(af, b1, D1, 0, 0, 0);
  }
  __syncthreads();  // all acc reads done; alias acc region as reduction buffer
  float* red = sm + ACC_OFF;
  *(f32x4*)&red[((wid * 2 + 0) * 64 + lane) * 4] = D0;
  *(f32x4*)&red[((wid * 2 + 1) * 64 + lane) * 4] = D1;
  __syncthreads();

  // ---- epilogue: 512 threads = 16 voxels x 32 cols ----
  int vv = tid >> 5, col = tid & 31;
  int nt = col >> 4, c16 = col & 15;
  int qq = vv >> 2, r = vv & 3;
  int lane2 = qq * 16 + c16;
  float sacc = 0.f;
#pragma unroll
  for (int w = 0; w < 8; ++w) sacc += red[((w * 2 + nt) * 64 + lane2) * 4 + r];
  float den = denS[vv];
  den = (den != 0.f) ? den : 1.f;
  float y = sacc * __builtin_amdgcn_rcpf(den) + bias[col];
  out[(size_t)(vbase + vv) * COUT + col] = fmaxf(y, 0.f);
}

extern "C" void kernel_launch(void* const* d_in, const int* in_sizes, int n_in,
                              void* d_out, int out_size, void* d_ws, size_t ws_size,
                              hipStream_t stream) {
  const float* feats = (const float*)d_in[0];
  const float* inp_pts = (const float*)d_in[1];
  const float* out_pts = (const float*)d_in[2];
  const float* out_ext = (const float*)d_in[3];
  const float* scale = (const float*)d_in[4];
  const float* ndist = (const float*)d_in[5];
  const int* nidx = (const int*)d_in[6];
  const int* rsp = (const int*)d_in[7];
  const float* kern = (const float*)d_in[8];
  const float* bias = (const float*)d_in[9];
  __bf16* wsB = (__bf16*)d_ws;

  prep_kernel<<<128, 256, 0, stream>>>(kern, wsB);
  cconv_kernel<<<N_OUT / VPB, THREADS, 0, stream>>>(
      feats, inp_pts, out_pts, out_ext, scale, ndist, nidx, rsp, bias, wsB,
      (float*)d_out);
}

// Round 7
// 163.671 us; speedup vs baseline: 6.5527x; 1.0111x over previous
//
#include <hip/hip_runtime.h>
#include <stdint.h>

#define N_OUT 100000
#define CIN 16
#define COUT 32
#define VPB 16
#define THREADS 512
#define CHUNK 16

// LDS layout (dword offsets). PSI+REC (loop phase) alias ACC (post-loop):
// they never coexist -- barriers separate last stage-A read from C-write.
#define ACC_OFF 0
#define ACC_VSTRIDE 580   // dwords/voxel: 16 ch * 36 + 4 pad
#define ACC_CSTRIDE 36    // dwords/channel: 64 taps * 2B -> 144B
#define PSI_OFF 0
#define PSI_VSTRIDE 200   // 16 ch * 12 + 8 pad
#define PSI_CSTRIDE 12    // dwords/channel row: 16 slots * 2B -> 48B
#define REC_OFF 3200      // [16 v][16 slots][4 floats] = 1024 dw
#define RSP_OFF 9280
#define DEN_OFF 9297
#define CMAX_OFF 9313
#define SMEM_DW 9316      // 37264 B -> 4 blocks/CU (149 KB of 160 KB)

typedef __attribute__((ext_vector_type(4))) float f32x4;
typedef __attribute__((ext_vector_type(8))) __bf16 bf16x8;
typedef __attribute__((ext_vector_type(4))) __bf16 bf16x4;
typedef __attribute__((ext_vector_type(4))) short s16x4;  // short4 is a HIP type

__device__ __forceinline__ float clampf(float x, float lo, float hi) {
  return fminf(fmaxf(x, lo), hi);
}
__device__ __forceinline__ float hatf(float x) {
  return fmaxf(0.f, 1.f - fabsf(x));
}

// prep: kernel fp32 [64 taps][16 cin][32 cout] -> bf16 MFMA B-fragments,
// K permuted as k = cin*64 + tap. (validated R1-R6; stage B only)
__global__ void prep_kernel(const float* __restrict__ kern, __bf16* __restrict__ wsB) {
  int t = blockIdx.x * blockDim.x + threadIdx.x;  // 0..32767
  int j = t & 7;
  int lane = (t >> 3) & 63;
  int ntile = (t >> 9) & 1;
  int kchunk = t >> 10;
  int k = kchunk * 32 + (lane >> 4) * 8 + j;
  int tap = k & 63;
  int cin = k >> 6;
  int o = ntile * 16 + (lane & 15);
  wsB[t] = (__bf16)kern[(tap * CIN + cin) * COUT + o];
}

// launch_bounds 2nd arg = min BLOCKS/CU (empirical R2/R3/R4): 4 blocks ->
// 8 waves/EU -> 64-VGPR cap. R6 measured 48 VGPR; headroom is safe.
__global__ __launch_bounds__(THREADS, 4) void cconv_kernel(
    const float* __restrict__ feats, const float* __restrict__ inp_pts,
    const float* __restrict__ out_pts, const float* __restrict__ out_ext,
    const float* __restrict__ scale, const float* __restrict__ ndist,
    const int* __restrict__ nidx, const int* __restrict__ rsp,
    const float* __restrict__ bias, const __bf16* __restrict__ wsB,
    float* __restrict__ out) {
  __shared__ __align__(16) float sm[SMEM_DW];
  int* rsp_s = (int*)(sm + RSP_OFF);
  float* denS = sm + DEN_OFF;
  int* cmax_p = (int*)(sm + CMAX_OFF);

  int tid = threadIdx.x;
  int vbase = blockIdx.x * VPB;

  if (tid < VPB + 1) rsp_s[tid] = rsp[vbase + tid];
  if (tid < VPB) denS[tid] = 0.f;
  __syncthreads();
  if (tid < VPB) {
    int cm = rsp_s[tid + 1] - rsp_s[tid];
    cm = max(cm, __shfl_xor(cm, 1));
    cm = max(cm, __shfl_xor(cm, 2));
    cm = max(cm, __shfl_xor(cm, 4));
    cm = max(cm, __shfl_xor(cm, 8));
    if (tid == 0) *cmax_p = cm;
  }
  __syncthreads();
  int cmax = *cmax_p;

  int wid = tid >> 6, lane = tid & 63;
  int q = lane >> 4, l15 = lane & 15;

  f32x4 DA[2][4] = {};  // stage-A accumulators: 2 voxels x 4 tap-tiles

  for (int c0 = 0; c0 < cmax; c0 += CHUNK) {
    // ---- staging, split across all 8 waves ----
    // imp is folded into W (stage A), so psi = raw bf16 feats: the psi group
    // (threads 256-511) is independent of the geometry group (threads 0-255).
    if (tid < 256) {
      // geometry -> rec + denominator
      int v = tid >> 4, slot = tid & 15;
      int cnt = rsp_s[v + 1] - rsp_s[v];
      bool valid = (c0 + slot) < cnt;
      float tx = 0.f, ty = 0.f, tz = 0.f, imp = 0.f;
      if (valid) {
        int e = rsp_s[v] + c0 + slot;
        int n = vbase + v;
        int nbr = nidx[e];
        float dsq = ndist[e];
        float p6 = 1.f - dsq;
        p6 = p6 * p6 * p6;
        p6 = clampf(p6, 0.f, 1.f);
        imp = scale[e] * p6;
        float inv = 2.f * __builtin_amdgcn_rcpf(out_ext[n]);
        float rx = (inp_pts[nbr * 3 + 0] - out_pts[n * 3 + 0]) * inv;
        float ry = (inp_pts[nbr * 3 + 1] - out_pts[n * 3 + 1]) * inv;
        float rz = (inp_pts[nbr * 3 + 2] - out_pts[n * 3 + 2]) * inv;
        float l2 = __builtin_amdgcn_sqrtf(rx * rx + ry * ry + rz * rz);
        float linf = fmaxf(fabsf(rx), fmaxf(fabsf(ry), fabsf(rz)));
        float s = (linf > 0.f)
                      ? (l2 * __builtin_amdgcn_rcpf(fmaxf(linf, 1e-12f)))
                      : 0.f;
        float qx = clampf(rx * s, -1.f, 1.f);
        float qy = clampf(ry * s, -1.f, 1.f);
        float qz = clampf(rz * s, -1.f, 1.f);
        tx = (qx + 1.f) * 1.5f;
        ty = (qy + 1.f) * 1.5f;
        tz = (qz + 1.f) * 1.5f;
      }
      f32x4 r4 = {tx, ty, tz, imp};
      *(f32x4*)(sm + REC_OFF + (v * 16 + slot) * 4) = r4;
      float r = imp;
      r += __shfl_xor(r, 1);
      r += __shfl_xor(r, 2);
      r += __shfl_xor(r, 4);
      r += __shfl_xor(r, 8);
      if (slot == 0) denS[v] += r;
    } else {
      // feats gather -> psi (bf16, no imp scaling)
      int t2 = tid - 256;
      int v = t2 >> 4, slot = t2 & 15;
      int cnt = rsp_s[v + 1] - rsp_s[v];
      bool valid = (c0 + slot) < cnt;
      __bf16* pt = (__bf16*)(sm + PSI_OFF + v * PSI_VSTRIDE);
      if (valid) {
        int e = rsp_s[v] + c0 + slot;
        int nbr = nidx[e];
        const f32x4* fp = (const f32x4*)(feats + (size_t)nbr * CIN);
#pragma unroll
        for (int g = 0; g < 4; ++g) {
          f32x4 fg = fp[g];
#pragma unroll
          for (int c4 = 0; c4 < 4; ++c4)
            pt[(g * 4 + c4) * (PSI_CSTRIDE * 2) + slot] = (__bf16)fg[c4];
        }
      } else {
#pragma unroll
        for (int c = 0; c < CIN; ++c) pt[c * (PSI_CSTRIDE * 2) + slot] = (__bf16)0.f;
      }
    }
    __syncthreads();
    // ---- stage A: acc[v][64 taps][16 ch] = (W*imp) * psi, wave -> 2 voxels
    // Invalid slots have imp==0 -> W==0 there: no guard needed.
#pragma unroll
    for (int vi = 0; vi < 2; ++vi) {
      int v = wid * 2 + vi;
      float m1 = (float)(l15 >> 2);  // iy of this lane's taps
      float m0 = (float)(l15 & 3);   // iz
#if __has_builtin(__builtin_amdgcn_mfma_f32_16x16x16bf16_1k)
      // K=16: slot = q*4+j. B-frag: psi[ch=l15][slot q*4..+3] (one b64).
      s16x4 bs = *(const s16x4*)(
          (const __bf16*)(sm + PSI_OFF + v * PSI_VSTRIDE) + l15 * (PSI_CSTRIDE * 2) + q * 4);
      float w[4][4];
#pragma unroll
      for (int j = 0; j < 4; ++j) {
        f32x4 r4 = *(const f32x4*)(sm + REC_OFF + (v * 16 + q * 4 + j) * 4);
        float wyz = hatf(r4[1] - m1) * hatf(r4[2] - m0) * r4[3];
        w[0][j] = hatf(r4[0]) * wyz;
        w[1][j] = hatf(r4[0] - 1.f) * wyz;
        w[2][j] = hatf(r4[0] - 2.f) * wyz;
        w[3][j] = hatf(r4[0] - 3.f) * wyz;
      }
#pragma unroll
      for (int t = 0; t < 4; ++t) {
        bf16x4 af;
        af[0] = (__bf16)w[t][0]; af[1] = (__bf16)w[t][1];
        af[2] = (__bf16)w[t][2]; af[3] = (__bf16)w[t][3];
        DA[vi][t] = __builtin_amdgcn_mfma_f32_16x16x16bf16_1k(
            *(s16x4*)&af, bs, DA[vi][t], 0, 0, 0);
      }
#else
      // fallback: K=32 with zero-padded upper half
      int qc = (q < 2) ? q : 1;
      bf16x8 bfrag = *(const bf16x8*)(
          (const __bf16*)(sm + PSI_OFF + v * PSI_VSTRIDE) + l15 * (PSI_CSTRIDE * 2) + qc * 8);
      bf16x8 af0, af1, af2, af3;
#pragma unroll
      for (int j = 0; j < 8; ++j) {
        int s = q * 8 + j;
        float w0 = 0.f, w1 = 0.f, w2 = 0.f, w3 = 0.f;
        if (s < 16) {
          f32x4 r4 = *(const f32x4*)(sm + REC_OFF + (v * 16 + s) * 4);
          float wyz = hatf(r4[1] - m1) * hatf(r4[2] - m0) * r4[3];
          w0 = hatf(r4[0]) * wyz;
          w1 = hatf(r4[0] - 1.f) * wyz;
          w2 = hatf(r4[0] - 2.f) * wyz;
          w3 = hatf(r4[0] - 3.f) * wyz;
        }
        af0[j] = (__bf16)w0; af1[j] = (__bf16)w1;
        af2[j] = (__bf16)w2; af3[j] = (__bf16)w3;
      }
      DA[vi][0] = __builtin_amdgcn_mfma_f32_16x16x32_bf16(af0, bfrag, DA[vi][0], 0, 0, 0);
      DA[vi][1] = __builtin_amdgcn_mfma_f32_16x16x32_bf16(af1, bfrag, DA[vi][1], 0, 0, 0);
      DA[vi][2] = __builtin_amdgcn_mfma_f32_16x16x32_bf16(af2, bfrag, DA[vi][2], 0, 0, 0);
      DA[vi][3] = __builtin_amdgcn_mfma_f32_16x16x32_bf16(af3, bfrag, DA[vi][3], 0, 0, 0);
#endif
    }
    __syncthreads();  // also separates stage-A psi/rec reads from ACC overwrite
  }

  // ---- write stage-A C (taps t*16+q*4+r, ch=l15) to acc as bf16 ----
#pragma unroll
  for (int vi = 0; vi < 2; ++vi) {
    int v = wid * 2 + vi;
    __bf16* ab = (__bf16*)(sm + ACC_OFF + v * ACC_VSTRIDE + l15 * ACC_CSTRIDE);
#pragma unroll
    for (int t = 0; t < 4; ++t) {
      bf16x4 pk;
      pk[0] = (__bf16)DA[vi][t][0]; pk[1] = (__bf16)DA[vi][t][1];
      pk[2] = (__bf16)DA[vi][t][2]; pk[3] = (__bf16)DA[vi][t][3];
      *(bf16x4*)(ab + t * 16 + q * 4) = pk;
    }
  }
  __syncthreads();

  // ---- stage B: [16 x 1024] x [1024 x 32], k = ch*64 + tap ----
  f32x4 D0 = {0.f, 0.f, 0.f, 0.f};
  f32x4 D1 = {0.f, 0.f, 0.f, 0.f};
  const __bf16* accv = (const __bf16*)(sm + ACC_OFF + l15 * ACC_VSTRIDE);
#pragma unroll
  for (int kc = 0; kc < 4; ++kc) {
    int kchunk = wid * 4 + kc;
    int c = kchunk >> 1;
    int tap = (kchunk & 1) * 32 + q * 8;
    bf16x8 af = *(const bf16x8*)(accv + c * (ACC_CSTRIDE * 2) + tap);
    bf16x8 b0 = *(const bf16x8*)(wsB + ((kchunk * 2 + 0) * 64 + lane) * 8);
    bf16x8 b1 = *(const bf16x8*)(wsB + ((kchunk * 2 + 1) * 64 + lane) * 8);
    D0 = __builtin_amdgcn_mfma_f32_16x16x32_bf16(af, b0, D0, 0, 0, 0);
    D1 = __builtin_amdgcn_mfma_f32_16x16x32_bf16(af, b1, D1, 0, 0, 0);
  }
  __syncthreads();  // all acc reads done; alias acc region as reduction buffer
  float* red = sm + ACC_OFF;
  *(f32x4*)&red[((wid * 2 + 0) * 64 + lane) * 4] = D0;
  *(f32x4*)&red[((wid * 2 + 1) * 64 + lane) * 4] = D1;
  __syncthreads();

  // ---- epilogue: 512 threads = 16 voxels x 32 cols ----
  int vv = tid >> 5, col = tid & 31;
  int nt = col >> 4, c16 = col & 15;
  int qq = vv >> 2, r = vv & 3;
  int lane2 = qq * 16 + c16;
  float sacc = 0.f;
#pragma unroll
  for (int w = 0; w < 8; ++w) sacc += red[((w * 2 + nt) * 64 + lane2) * 4 + r];
  float den = denS[vv];
  den = (den != 0.f) ? den : 1.f;
  float y = sacc * __builtin_amdgcn_rcpf(den) + bias[col];
  out[(size_t)(vbase + vv) * COUT + col] = fmaxf(y, 0.f);
}

extern "C" void kernel_launch(void* const* d_in, const int* in_sizes, int n_in,
                              void* d_out, int out_size, void* d_ws, size_t ws_size,
                              hipStream_t stream) {
  const float* feats = (const float*)d_in[0];
  const float* inp_pts = (const float*)d_in[1];
  const float* out_pts = (const float*)d_in[2];
  const float* out_ext = (const float*)d_in[3];
  const float* scale = (const float*)d_in[4];
  const float* ndist = (const float*)d_in[5];
  const int* nidx = (const int*)d_in[6];
  const int* rsp = (const int*)d_in[7];
  const float* kern = (const float*)d_in[8];
  const float* bias = (const float*)d_in[9];
  __bf16* wsB = (__bf16*)d_ws;

  prep_kernel<<<128, 256, 0, stream>>>(kern, wsB);
  cconv_kernel<<<N_OUT / VPB, THREADS, 0, stream>>>(
      feats, inp_pts, out_pts, out_ext, scale, ndist, nidx, rsp, bias, wsB,
      (float*)d_out);
}

// Round 8
// 160.302 us; speedup vs baseline: 6.6904x; 1.0210x over previous
//
#include <hip/hip_runtime.h>
#include <stdint.h>

#define N_OUT 100000
#define KNBR 14          // edges per voxel: neighbors_row_splits = arange*14 (fixed input)
#define CIN 16
#define COUT 32
#define VPB 16
#define THREADS 512
#define GROUPS (N_OUT / VPB)  // 6250
#define NB 768                // persistent blocks: 3/CU * 256 CU

// LDS layout (dword offsets). PSI+REC+RED alias ACC; phases separated by barriers.
#define ACC_OFF 0
#define ACC_VSTRIDE 580   // dwords/voxel: 16 ch * 36 + 4 pad
#define ACC_CSTRIDE 36    // dwords/channel: 64 taps * 2B -> 144B
#define PSI_OFF 0
#define PSI_VSTRIDE 200
#define PSI_CSTRIDE 12
#define REC_OFF 3200      // [16 v][16 slots][4 floats]
#define DEN_OFF 9280
#define SMEM_DW 9296      // 37184 B

typedef __attribute__((ext_vector_type(4))) float f32x4;
typedef __attribute__((ext_vector_type(8))) __bf16 bf16x8;
typedef __attribute__((ext_vector_type(4))) __bf16 bf16x4;
typedef __attribute__((ext_vector_type(4))) short s16x4;  // short4 is a HIP type

__device__ __forceinline__ float clampf(float x, float lo, float hi) {
  return fminf(fmaxf(x, lo), hi);
}
__device__ __forceinline__ float hatf(float x) {
  return fmaxf(0.f, 1.f - fabsf(x));
}
// LDS-only barrier: drain lgkmcnt, leave vmcnt outstanding (prefetch survives).
// imm encoding: vmcnt=63 (bits[3:0]=0xF, [15:14]=0x3), expcnt=7, lgkmcnt=0.
__device__ __forceinline__ void barrier_lds() {
  __builtin_amdgcn_s_waitcnt(0xC07F);
  __builtin_amdgcn_s_barrier();
}

// prep: kernel fp32 [64 taps][16 cin][32 cout] -> bf16 MFMA B-fragments,
// K permuted as k = cin*64 + tap. (validated R1-R7; stage B)
__global__ void prep_kernel(const float* __restrict__ kern, __bf16* __restrict__ wsB) {
  int t = blockIdx.x * blockDim.x + threadIdx.x;  // 0..32767
  int j = t & 7;
  int lane = (t >> 3) & 63;
  int ntile = (t >> 9) & 1;
  int kchunk = t >> 10;
  int k = kchunk * 32 + (lane >> 4) * 8 + j;
  int tap = k & 63;
  int cin = k >> 6;
  int o = ntile * 16 + (lane & 15);
  wsB[t] = (__bf16)kern[(tap * CIN + cin) * COUT + o];
}

// launch_bounds 2nd arg = min BLOCKS/CU (empirical R2-R4): 3 -> ~85 VGPR cap.
__global__ __launch_bounds__(THREADS, 3) void cconv_kernel(
    const float* __restrict__ feats, const float* __restrict__ inp_pts,
    const float* __restrict__ out_pts, const float* __restrict__ out_ext,
    const float* __restrict__ scale, const float* __restrict__ ndist,
    const int* __restrict__ nidx,
    const float* __restrict__ bias, const __bf16* __restrict__ wsB,
    float* __restrict__ out) {
  __shared__ __align__(16) float sm[SMEM_DW];
  float* denS = sm + DEN_OFF;

  int tid = threadIdx.x;
  int wid = tid >> 6, lane = tid & 63;
  int q = lane >> 4, l15 = lane & 15;
  bool isPsi = tid >= 256;
  int t2 = tid & 255;
  int v = t2 >> 4, slot = t2 & 15;
  bool slotValid = slot < KNBR;

  // ---- prologue: load group g0, prefetch nidx for g0+NB ----
  int g0 = blockIdx.x;
  float sc = 0.f, nd = 0.f, px = 0.f, py = 0.f, pz = 0.f;
  float ox = 0.f, oy = 0.f, oz = 0.f, ex = 1.f;
  f32x4 cf0 = {}, cf1 = {}, cf2 = {}, cf3 = {};
  int nidxNxt = 0;
  {
    int n = g0 * VPB + v;
    long e = (long)n * KNBR + slot;
    int nb = slotValid ? nidx[e] : 0;
    if (!isPsi) {
      ox = out_pts[n * 3 + 0]; oy = out_pts[n * 3 + 1]; oz = out_pts[n * 3 + 2];
      ex = out_ext[n];
      if (slotValid) {
        sc = scale[e]; nd = ndist[e];
        px = inp_pts[nb * 3 + 0]; py = inp_pts[nb * 3 + 1]; pz = inp_pts[nb * 3 + 2];
      }
    } else if (slotValid) {
      const f32x4* fp = (const f32x4*)(feats + (size_t)nb * CIN);
      cf0 = fp[0]; cf1 = fp[1]; cf2 = fp[2]; cf3 = fp[3];
    }
    int g1 = g0 + NB;
    if (g1 < GROUPS && slotValid) nidxNxt = nidx[(long)(g1 * VPB + v) * KNBR + slot];
  }

  for (int g = g0; g < GROUPS; g += NB) {
    // ---- phase 1: consume current regs -> LDS ----
    if (!isPsi) {
      float tx = 0.f, ty = 0.f, tz = 0.f, imp = 0.f;
      if (slotValid) {
        float p6 = 1.f - nd;
        p6 = p6 * p6 * p6;
        p6 = clampf(p6, 0.f, 1.f);
        imp = sc * p6;
        float inv = 2.f * __builtin_amdgcn_rcpf(ex);
        float rx = (px - ox) * inv, ry = (py - oy) * inv, rz = (pz - oz) * inv;
        float l2 = __builtin_amdgcn_sqrtf(rx * rx + ry * ry + rz * rz);
        float linf = fmaxf(fabsf(rx), fmaxf(fabsf(ry), fabsf(rz)));
        float s = (linf > 0.f) ? (l2 * __builtin_amdgcn_rcpf(fmaxf(linf, 1e-12f))) : 0.f;
        tx = (clampf(rx * s, -1.f, 1.f) + 1.f) * 1.5f;
        ty = (clampf(ry * s, -1.f, 1.f) + 1.f) * 1.5f;
        tz = (clampf(rz * s, -1.f, 1.f) + 1.f) * 1.5f;
      }
      f32x4 r4 = {tx, ty, tz, imp};
      *(f32x4*)(sm + REC_OFF + (v * 16 + slot) * 4) = r4;
      float r = imp;
      r += __shfl_xor(r, 1);
      r += __shfl_xor(r, 2);
      r += __shfl_xor(r, 4);
      r += __shfl_xor(r, 8);
      if (slot == 0) denS[v] = r;
    } else {
      __bf16* pt = (__bf16*)(sm + PSI_OFF + v * PSI_VSTRIDE);
      if (slotValid) {
        float fv[16] = {cf0[0], cf0[1], cf0[2], cf0[3], cf1[0], cf1[1], cf1[2], cf1[3],
                        cf2[0], cf2[1], cf2[2], cf2[3], cf3[0], cf3[1], cf3[2], cf3[3]};
#pragma unroll
        for (int c = 0; c < CIN; ++c) pt[c * (PSI_CSTRIDE * 2) + slot] = (__bf16)fv[c];
      } else {
#pragma unroll
        for (int c = 0; c < CIN; ++c) pt[c * (PSI_CSTRIDE * 2) + slot] = (__bf16)0.f;
      }
    }
    // ---- phase 1b: issue prefetch for g+NB (hidden under stages A/B) ----
    {
      int gN = g + NB, gNN = g + 2 * NB;
      if (gN < GROUPS) {
        int n = gN * VPB + v;
        long e = (long)n * KNBR + slot;
        int nb = nidxNxt;
        if (!isPsi) {
          ox = out_pts[n * 3 + 0]; oy = out_pts[n * 3 + 1]; oz = out_pts[n * 3 + 2];
          ex = out_ext[n];
          if (slotValid) {
            sc = scale[e]; nd = ndist[e];
            px = inp_pts[nb * 3 + 0]; py = inp_pts[nb * 3 + 1]; pz = inp_pts[nb * 3 + 2];
          }
        } else if (slotValid) {
          const f32x4* fp = (const f32x4*)(feats + (size_t)nb * CIN);
          cf0 = fp[0]; cf1 = fp[1]; cf2 = fp[2]; cf3 = fp[3];
        }
        if (gNN < GROUPS && slotValid)
          nidxNxt = nidx[(long)(gNN * VPB + v) * KNBR + slot];
      }
    }
    barrier_lds();  // B1: rec/psi visible

    // ---- stage A: acc[v][64 taps][16 ch] = (W*imp) * psi, wave -> 2 voxels
    f32x4 DA[2][4] = {};
#pragma unroll
    for (int vi = 0; vi < 2; ++vi) {
      int vv2 = wid * 2 + vi;
      float m1 = (float)(l15 >> 2);
      float m0 = (float)(l15 & 3);
#if __has_builtin(__builtin_amdgcn_mfma_f32_16x16x16bf16_1k)
      s16x4 bs = *(const s16x4*)(
          (const __bf16*)(sm + PSI_OFF + vv2 * PSI_VSTRIDE) + l15 * (PSI_CSTRIDE * 2) + q * 4);
      float w[4][4];
#pragma unroll
      for (int j = 0; j < 4; ++j) {
        f32x4 r4 = *(const f32x4*)(sm + REC_OFF + (vv2 * 16 + q * 4 + j) * 4);
        float wyz = hatf(r4[1] - m1) * hatf(r4[2] - m0) * r4[3];
        w[0][j] = hatf(r4[0]) * wyz;
        w[1][j] = hatf(r4[0] - 1.f) * wyz;
        w[2][j] = hatf(r4[0] - 2.f) * wyz;
        w[3][j] = hatf(r4[0] - 3.f) * wyz;
      }
#pragma unroll
      for (int t = 0; t < 4; ++t) {
        bf16x4 af;
        af[0] = (__bf16)w[t][0]; af[1] = (__bf16)w[t][1];
        af[2] = (__bf16)w[t][2]; af[3] = (__bf16)w[t][3];
        DA[vi][t] = __builtin_amdgcn_mfma_f32_16x16x16bf16_1k(
            *(s16x4*)&af, bs, DA[vi][t], 0, 0, 0);
      }
#else
      int qc = (q < 2) ? q : 1;
      bf16x8 bfrag = *(const bf16x8*)(
          (const __bf16*)(sm + PSI_OFF + vv2 * PSI_VSTRIDE) + l15 * (PSI_CSTRIDE * 2) + qc * 8);
      bf16x8 af0, af1, af2, af3;
#pragma unroll
      for (int j = 0; j < 8; ++j) {
        int s = q * 8 + j;
        float w0 = 0.f, w1 = 0.f, w2 = 0.f, w3 = 0.f;
        if (s < 16) {
          f32x4 r4 = *(const f32x4*)(sm + REC_OFF + (vv2 * 16 + s) * 4);
          float wyz = hatf(r4[1] - m1) * hatf(r4[2] - m0) * r4[3];
          w0 = hatf(r4[0]) * wyz;
          w1 = hatf(r4[0] - 1.f) * wyz;
          w2 = hatf(r4[0] - 2.f) * wyz;
          w3 = hatf(r4[0] - 3.f) * wyz;
        }
        af0[j] = (__bf16)w0; af1[j] = (__bf16)w1;
        af2[j] = (__bf16)w2; af3[j] = (__bf16)w3;
      }
      DA[vi][0] = __builtin_amdgcn_mfma_f32_16x16x32_bf16(af0, bfrag, DA[vi][0], 0, 0, 0);
      DA[vi][1] = __builtin_amdgcn_mfma_f32_16x16x32_bf16(af1, bfrag, DA[vi][1], 0, 0, 0);
      DA[vi][2] = __builtin_amdgcn_mfma_f32_16x16x32_bf16(af2, bfrag, DA[vi][2], 0, 0, 0);
      DA[vi][3] = __builtin_amdgcn_mfma_f32_16x16x32_bf16(af3, bfrag, DA[vi][3], 0, 0, 0);
#endif
    }
    barrier_lds();  // B2: stage-A psi/rec reads done before ACC overwrite

    // ---- write stage-A C to acc as bf16 ----
#pragma unroll
    for (int vi = 0; vi < 2; ++vi) {
      int vv2 = wid * 2 + vi;
      __bf16* ab = (__bf16*)(sm + ACC_OFF + vv2 * ACC_VSTRIDE + l15 * ACC_CSTRIDE);
#pragma unroll
      for (int t = 0; t < 4; ++t) {
        bf16x4 pk;
        pk[0] = (__bf16)DA[vi][t][0]; pk[1] = (__bf16)DA[vi][t][1];
        pk[2] = (__bf16)DA[vi][t][2]; pk[3] = (__bf16)DA[vi][t][3];
        *(bf16x4*)(ab + t * 16 + q * 4) = pk;
      }
    }
    barrier_lds();  // B3: acc visible

    // ---- stage B: [16 x 1024] x [1024 x 32], k = ch*64 + tap ----
    f32x4 D0 = {0.f, 0.f, 0.f, 0.f};
    f32x4 D1 = {0.f, 0.f, 0.f, 0.f};
    const __bf16* accv = (const __bf16*)(sm + ACC_OFF + l15 * ACC_VSTRIDE);
#pragma unroll
    for (int kc = 0; kc < 4; ++kc) {
      int kchunk = wid * 4 + kc;
      int c = kchunk >> 1;
      int tap = (kchunk & 1) * 32 + q * 8;
      bf16x8 af = *(const bf16x8*)(accv + c * (ACC_CSTRIDE * 2) + tap);
      bf16x8 b0 = *(const bf16x8*)(wsB + ((kchunk * 2 + 0) * 64 + lane) * 8);
      bf16x8 b1 = *(const bf16x8*)(wsB + ((kchunk * 2 + 1) * 64 + lane) * 8);
      D0 = __builtin_amdgcn_mfma_f32_16x16x32_bf16(af, b0, D0, 0, 0, 0);
      D1 = __builtin_amdgcn_mfma_f32_16x16x32_bf16(af, b1, D1, 0, 0, 0);
    }
    barrier_lds();  // B4: acc reads done; alias as reduction buffer
    float* red = sm + ACC_OFF;
    *(f32x4*)&red[((wid * 2 + 0) * 64 + lane) * 4] = D0;
    *(f32x4*)&red[((wid * 2 + 1) * 64 + lane) * 4] = D1;
    barrier_lds();  // B5: red visible

    // ---- epilogue: 512 threads = 16 voxels x 32 cols ----
    {
      int vv2 = tid >> 5, col = tid & 31;
      int nt = col >> 4, c16 = col & 15;
      int qq = vv2 >> 2, r = vv2 & 3;
      int lane2 = qq * 16 + c16;
      float sacc = 0.f;
#pragma unroll
      for (int w = 0; w < 8; ++w) sacc += red[((w * 2 + nt) * 64 + lane2) * 4 + r];
      float den = denS[vv2];
      den = (den != 0.f) ? den : 1.f;
      float y = sacc * __builtin_amdgcn_rcpf(den) + bias[col];
      out[(size_t)(g * VPB + vv2) * COUT + col] = fmaxf(y, 0.f);
    }
    barrier_lds();  // B6: red reads done before next iteration's psi writes
  }
}

extern "C" void kernel_launch(void* const* d_in, const int* in_sizes, int n_in,
                              void* d_out, int out_size, void* d_ws, size_t ws_size,
                              hipStream_t stream) {
  const float* feats = (const float*)d_in[0];
  const float* inp_pts = (const float*)d_in[1];
  const float* out_pts = (const float*)d_in[2];
  const float* out_ext = (const float*)d_in[3];
  const float* scale = (const float*)d_in[4];
  const float* ndist = (const float*)d_in[5];
  const int* nidx = (const int*)d_in[6];
  const float* kern = (const float*)d_in[8];
  const float* bias = (const float*)d_in[9];
  __bf16* wsB = (__bf16*)d_ws;

  prep_kernel<<<128, 256, 0, stream>>>(kern, wsB);
  cconv_kernel<<<NB, THREADS, 0, stream>>>(
      feats, inp_pts, out_pts, out_ext, scale, ndist, nidx, bias, wsB,
      (float*)d_out);
}